// Round 1
// baseline (965.313 us; speedup 1.0000x reference)
//
#include <hip/hip_runtime.h>
#include <math.h>

// Problem constants (from reference)
#define Bn    256
#define Tn    1024
#define In    64
#define Pn    256
#define En    128
#define NOUTn 64
#define LN_EPS 1e-5f
#define TEMPc  8.0f

// LDS layout (floats):
//   mem  : Pn*En          = 32768   (per-batch ring memory, column e owned by one consumer lane)
//   embb : 2*En           = 256     (double-buffered emb[t])
//   xb   : 2*In           = 128     (double-buffered x[t])
//   jd   : Pn             = 256     (jump_dest copy)
#define LDS_FLOATS (Pn*En + 2*En + 2*In + Pn)
#define LDS_BYTES  (LDS_FLOATS * 4)

__global__ __launch_bounds__(192, 1)
void ring_kernel(const float* __restrict__ x,
                 const float* __restrict__ pointer_init,
                 const float* __restrict__ W_in,
                 const float* __restrict__ b_in,
                 const float* __restrict__ ln_w,
                 const float* __restrict__ ln_b,
                 const float* __restrict__ jump_dest,
                 const float* __restrict__ Wg,
                 const float* __restrict__ bg,
                 const float* __restrict__ cs_ptr,
                 const float* __restrict__ Wo,
                 const float* __restrict__ bo,
                 float* __restrict__ out)
{
    extern __shared__ float lds[];
    float* mem  = lds;                 // Pn*En
    float* embb = mem + Pn * En;       // 2*En
    float* xb   = embb + 2 * En;       // 2*In
    float* jd   = xb + 2 * In;         // Pn

    const int b   = blockIdx.x;
    const int tid = threadIdx.x;

    // ---- init: zero ring memory, copy jump_dest to LDS ----
    for (int i = tid; i < Pn * En; i += 192) mem[i] = 0.0f;
    for (int i = tid; i < Pn;      i += 192) jd[i]  = jump_dest[i];

    const float* xrow = x + (size_t)b * Tn * In;

    // consumer wave stages x[0], x[1]
    if (tid < 64) {
        xb[tid]      = xrow[tid];           // x[0] -> buffer 0
        xb[In + tid] = xrow[In + tid];      // x[1] -> buffer 1
    }
    __syncthreads();   // barrier #1: mem zeroed, x[0..1] staged, jd ready

    if (tid >= 64) {
        // ================= PRODUCER (waves 1,2): emb[t] pipeline =================
        const int p = tid - 64;            // channel 0..127
        float wr[In];
        {
            const float4* w4 = (const float4*)(W_in + p * In);
            #pragma unroll
            for (int i = 0; i < In / 4; ++i) {
                float4 v = w4[i];
                wr[4*i+0] = v.x; wr[4*i+1] = v.y; wr[4*i+2] = v.z; wr[4*i+3] = v.w;
            }
        }
        const float bi = b_in[p];

        // emb[0] from xb buffer 0
        {
            float acc = bi;
            #pragma unroll
            for (int i = 0; i < In; ++i) acc += wr[i] * xb[i];
            embb[p] = tanhf(acc);
        }
        __syncthreads();   // barrier A: emb[0] visible

        for (int t = 0; t < Tn; ++t) {
            if (t + 1 < Tn) {
                const float* xc = xb + ((t + 1) & 1) * In;   // x[t+1]
                float acc = bi;
                #pragma unroll
                for (int i = 0; i < In; ++i) acc += wr[i] * xc[i];
                embb[((t + 1) & 1) * En + p] = tanhf(acc);   // emb[t+1]
            }
            __syncthreads();   // end-of-step barrier
        }
    } else {
        // ================= CONSUMER (wave 0): the sequential scan =================
        const int l = tid;                 // lane; owns channels l and l+64
        const float lnw0 = ln_w[l],      lnw1 = ln_w[l + 64];
        const float lnb0 = ln_b[l],      lnb1 = ln_b[l + 64];
        const float wg0  = Wg[l],        wg1  = Wg[l + 64];
        const float bgs  = bg[0];
        const float cs   = 1.0f / (1.0f + expf(-cs_ptr[0]));   // sigmoid(context_strength)
        float hid0 = 0.0f, hid1 = 0.0f;
        float ptr  = pointer_init[b];
        __syncthreads();   // barrier A (match producer)

        for (int t = 0; t < Tn; ++t) {
            // --- prefetch x[t+2] into a register; LDS commit at bottom of step ---
            const bool do_stage = (t + 2 < Tn);
            float xs = 0.0f;
            if (do_stage) xs = xrow[(t + 2) * In + l];

            const float* embc = embb + (t & 1) * En;   // emb[t]

            // --- pointer-derived indices & softmax weights ---
            int base = (int)floorf(ptr);
            base = base < 0 ? 0 : (base > Pn - 1 ? Pn - 1 : base);
            int cur = (int)ptr;
            cur = cur < 0 ? 0 : (cur > Pn - 1 ? Pn - 1 : cur);
            const float jt = jd[cur];                  // jump target (off critical path)

            const float frac = ptr - (float)base;      // exact; delta_j = (j-2) - frac
            int   idx[5];
            float wgt[5];
            float mx = -3.4e38f;
            #pragma unroll
            for (int j = 0; j < 5; ++j) {
                idx[j] = (base + j - 2 + Pn) & (Pn - 1);
                float d = (float)(j - 2) - frac;       // bit-exact vs ref's mod formula here
                float s = -(d * d) * (1.0f / TEMPc);
                wgt[j] = s;
                mx = fmaxf(mx, s);
            }
            float se = 0.0f;
            #pragma unroll
            for (int j = 0; j < 5; ++j) { float ez = expf(wgt[j] - mx); wgt[j] = ez; se += ez; }
            const float inv = 1.0f / se;

            // --- gather neighborhood (lane-private LDS columns, no conflicts) ---
            float nb0[5], nb1[5];
            #pragma unroll
            for (int j = 0; j < 5; ++j) {
                nb0[j] = mem[idx[j] * En + l];
                nb1[j] = mem[idx[j] * En + 64 + l];
            }
            float ctx0 = 0.0f, ctx1 = 0.0f;
            #pragma unroll
            for (int j = 0; j < 5; ++j) {
                const float w = wgt[j] * inv; wgt[j] = w;
                ctx0 += w * nb0[j];
                ctx1 += w * nb1[j];
            }

            const float su0 = tanhf(embc[l]      + cs * ctx0 + hid0);
            const float su1 = tanhf(embc[l + 64] + cs * ctx1 + hid1);

            // --- fused scatter-add (indices distinct -> exact .at[].add) ---
            #pragma unroll
            for (int j = 0; j < 5; ++j) {
                mem[idx[j] * En + l]      = nb0[j] + wgt[j] * su0;
                mem[idx[j] * En + 64 + l] = nb1[j] + wgt[j] * su1;
            }

            // --- wave-local reductions: sum(su), sum(su^2), sum(su*Wg) ---
            float s1 = su0 + su1;
            float s2 = su0 * su0 + su1 * su1;
            float s3 = su0 * wg0 + su1 * wg1;
            #pragma unroll
            for (int off = 32; off > 0; off >>= 1) {
                s1 += __shfl_xor(s1, off, 64);
                s2 += __shfl_xor(s2, off, 64);
                s3 += __shfl_xor(s3, off, 64);
            }

            // --- layernorm -> hid ---
            const float mu   = s1 * (1.0f / En);
            const float var  = s2 * (1.0f / En) - mu * mu;
            const float rstd = rsqrtf(var + LN_EPS);
            hid0 = (su0 - mu) * rstd * lnw0 + lnb0;
            hid1 = (su1 - mu) * rstd * lnw1 + lnb1;

            // --- pointer update: sigmoid(jl) > 0.5  <=>  jl > 0 ---
            const float jl = s3 + bgs;
            float walk = ptr + 1.0f;
            if (walk >= 256.0f) walk -= 256.0f;       // == fmod(ptr+1, 256) for ptr in [0,256)
            ptr = (jl > 0.0f) ? jt : walk;

            // commit x[t+2] stage (vmcnt wait lands here, covered by the whole step)
            if (do_stage) xb[(t & 1) * In + l] = xs;
            __syncthreads();   // end-of-step barrier
        }
        // publish final hid for the output matmul (reuse embb buffer 0)
        embb[l]      = hid0;
        embb[l + 64] = hid1;
    }
    __syncthreads();

    // ---- epilogue: logits = hid @ Wo^T + bo ----
    if (tid < NOUTn) {
        const float* wrow = Wo + tid * En;
        float acc = bo[tid];
        #pragma unroll 4
        for (int e = 0; e < En; ++e) acc += embb[e] * wrow[e];
        out[b * NOUTn + tid] = acc;
    }
}

extern "C" void kernel_launch(void* const* d_in, const int* in_sizes, int n_in,
                              void* d_out, int out_size, void* d_ws, size_t ws_size,
                              hipStream_t stream) {
    const float* x            = (const float*)d_in[0];
    const float* pointer_init = (const float*)d_in[1];
    const float* W_in         = (const float*)d_in[2];
    const float* b_in         = (const float*)d_in[3];
    const float* ln_w         = (const float*)d_in[4];
    const float* ln_b         = (const float*)d_in[5];
    const float* jump_dest    = (const float*)d_in[6];
    const float* Wg           = (const float*)d_in[7];
    const float* bg           = (const float*)d_in[8];
    const float* cs           = (const float*)d_in[9];
    const float* Wo           = (const float*)d_in[10];
    const float* bo           = (const float*)d_in[11];
    float* out = (float*)d_out;

    // allow >64KB dynamic LDS (133632 B); idempotent, host-side, capture-safe
    (void)hipFuncSetAttribute((const void*)ring_kernel,
                              hipFuncAttributeMaxDynamicSharedMemorySize, LDS_BYTES);

    ring_kernel<<<Bn, 192, LDS_BYTES, stream>>>(
        x, pointer_init, W_in, b_in, ln_w, ln_b, jump_dest, Wg, bg, cs, Wo, bo, out);
}